// Round 3
// baseline (75.357 us; speedup 1.0000x reference)
//
#include <hip/hip_runtime.h>

constexpr int Cc   = 224;            // channels
constexpr int Tt   = 224;            // time steps
constexpr int TT   = 32;             // time tile (8 quads of 4)
constexpr int NT   = Tt / TT;        // 7
constexpr int ROWS = 236;            // row r <-> channel r-6 ; rows 0..5,230..235 = zero halo
constexpr int BUFW = ROWS * TT;      // 7552 words = 30208 B per buffer
constexpr int BDIM = 256;            // 4 waves, one batch per block

// async 16B-per-lane global->LDS; dest = wave-uniform base + lane*16
#define GLDS16(src, dst) __builtin_amdgcn_global_load_lds( \
    (const __attribute__((address_space(1))) unsigned int*)(src), \
    (__attribute__((address_space(3))) unsigned int*)(dst), 16, 0, 0)

// LDS layout: word(row, t) = row*32 + ((tq ^ (row&7))<<2) + (t&3), tq = t>>2
// (16B-slot XOR swizzle; staging pre-swizzles the global source so the
//  LDS destination stays linear per guide rule 21)

__global__ __launch_bounds__(BDIM, 2)
void cgss_snn_kernel(const float* __restrict__ x,
                     const float* __restrict__ wp,
                     float* __restrict__ out)
{
    __shared__ float lds[2 * BUFW];   // 60416 B -> 2 blocks/CU

    const int tid = threadIdx.x;
    const int w   = tid >> 6;         // wave id 0..3
    const int l   = tid & 63;
    const int b   = blockIdx.x;
    const long long bofs = (long long)b * (Cc * Tt);
    const float* xb = x + bofs;
    float*       ob = out + bofs;

    // ---- zero halo rows (0..5, 230..235) in both buffers, once ----
    if (tid < 192) {                       // 12 rows * 8 slots * 2 bufs
        int bufi = tid / 96;
        int q    = tid - 96 * bufi;
        int rr   = q >> 3;                 // 0..11
        int slot = q & 7;
        int row  = (rr < 6) ? rr : (224 + rr);   // 0..5, 230..235
        float4 z = make_float4(0.f, 0.f, 0.f, 0.f);
        *reinterpret_cast<float4*>(&lds[bufi * BUFW + row * 32 + slot * 4]) = z;
    }

    // ---- async stage of one time tile: 28 full-wave chunks (rows 6..229) ----
    // chunk j covers rows 6+8j .. 13+8j ; wave w handles chunks 7w..7w+6
    const int srow = l >> 3;                       // row-in-chunk 0..7
    const int stq  = (l & 7) ^ ((6 + srow) & 7);   // t-quad this lane fetches
    auto stage = [&](int bufi, int t0) {
        float* base = &lds[bufi * BUFW];
#pragma unroll
        for (int i = 0; i < 7; ++i) {
            int j   = 7 * w + i;
            int row = 6 + 8 * j + srow;
            const float* src = xb + (row - 6) * Tt + t0 + stq * 4;
            GLDS16(src, &base[(6 + 8 * j) * 32]);
        }
    };

    stage(0, 0);    // tile 0 in flight while we compute the gaussian kernel

    // ---- gaussian kernel (arithmetic identical to verified rounds 1-2) ----
    float kr[13];
    {
        float wv = wp[0];
        float wc = fminf(fmaxf(wv, 0.4f), 10.0f);
        float norm = 0.0f;
        const float step = 120.0f / 129.0f;
        for (int j = 0; j < 130; ++j) {
            float r = -60.0f + (float)j * step;
            float z = r / wc;
            norm += expf(-0.5f * z * z);
        }
        for (int i = 0; i < 13; ++i) {
            float r = (float)(i - 6);
            float z = r / wc;
            kr[i] = expf(-0.5f * z * z) / norm;
        }
    }

    float mem = 0.0f, rstv = 0.0f;    // LIF state, carried across tiles
    int bufc = 0;

    asm volatile("s_waitcnt vmcnt(0)" ::: "memory");
    __syncthreads();                  // buf0 ready for all waves

    for (int tile = 0; tile < NT; ++tile) {
        const int t0 = tile * TT;
        if (tile < NT - 1) stage(bufc ^ 1, t0 + TT);   // overlap next-tile HBM

        // ---- conv + LIF: thread c owns channel c; 13 ds_read_b128 per quad ----
        unsigned m = 0;
        if (tid < Cc) {
            const char* sb = (const char*)&lds[bufc * BUFW];
#pragma unroll 2
            for (int tq = 0; tq < 8; ++tq) {
                float4 v[13];
#pragma unroll
                for (int k = 0; k < 13; ++k) {
                    int row = tid + k;
                    v[k] = *reinterpret_cast<const float4*>(
                        sb + row * 128 + ((tq ^ (row & 7)) << 4));
                }
                float4 acc = make_float4(0.f, 0.f, 0.f, 0.f);
#pragma unroll
                for (int k = 0; k < 13; ++k) {
                    float kk = kr[k];
                    acc.x += kk * v[k].x;  acc.y += kk * v[k].y;
                    acc.z += kk * v[k].z;  acc.w += kk * v[k].w;
                }
                const float* xv = (const float*)&v[6];
                const float* av = (const float*)&acc;
#pragma unroll
                for (int s = 0; s < 4; ++s) {
                    float d  = xv[s] - av[s];
                    float rl = d > 0.0f ? d : 0.0f;
                    float I  = xv[s] - rl;
                    mem = 0.97f * mem + I - rstv;
                    bool sp = mem > 1.0f;
                    rstv = sp ? 1.0f : 0.0f;
                    m |= sp ? (1u << (4 * tq + s)) : 0u;
                }
            }
        }
        __syncthreads();              // everyone done READING bufc

        // ---- expand spike bits into the dead bufc (rows 0..223) ----
        if (tid < Cc) {
            char* sb = (char*)&lds[bufc * BUFW];
#pragma unroll
            for (int tq = 0; tq < 8; ++tq) {
                float4 sv;
                sv.x = (m >> (4 * tq + 0)) & 1 ? 1.0f : 0.0f;
                sv.y = (m >> (4 * tq + 1)) & 1 ? 1.0f : 0.0f;
                sv.z = (m >> (4 * tq + 2)) & 1 ? 1.0f : 0.0f;
                sv.w = (m >> (4 * tq + 3)) & 1 ? 1.0f : 0.0f;
                *reinterpret_cast<float4*>(
                    sb + tid * 128 + ((tq ^ (tid & 7)) << 4)) = sv;
            }
        }
        __syncthreads();              // spikes visible

        // ---- coalesced store: each instr fully covers 8 channel-rows of 128B ----
        {
            const char* sb = (const char*)&lds[bufc * BUFW];
            const int s = l & 7;
#pragma unroll
            for (int i = 0; i < 7; ++i) {
                int cr = 8 * (7 * w + i) + (l >> 3);
                float4 v = *reinterpret_cast<const float4*>(
                    sb + cr * 128 + ((s ^ (cr & 7)) << 4));
                *reinterpret_cast<float4*>(&ob[(long long)cr * Tt + t0 + 4 * s]) = v;
            }
        }

        asm volatile("s_waitcnt vmcnt(0)" ::: "memory");  // next-tile stage done
        __syncthreads();              // safe to overwrite bufc^1 readers / restage
        bufc ^= 1;
    }
}

extern "C" void kernel_launch(void* const* d_in, const int* in_sizes, int n_in,
                              void* d_out, int out_size, void* d_ws, size_t ws_size,
                              hipStream_t stream)
{
    const float* x  = (const float*)d_in[0];
    const float* w  = (const float*)d_in[1];
    float* out      = (float*)d_out;
    const int B = in_sizes[0] / (Cc * Tt);   // 512
    cgss_snn_kernel<<<B, BDIM, 0, stream>>>(x, w, out);
}